// Round 1
// baseline (302.925 us; speedup 1.0000x reference)
//
#include <hip/hip_runtime.h>
#include <hip/hip_bf16.h>

#define B_ 4
#define N_ 1024
#define C_ 1024
#define H_ 16
#define D_ 64

typedef __attribute__((ext_vector_type(8))) short bf16x8;
typedef __attribute__((ext_vector_type(4))) float f32x4;

__device__ __forceinline__ void gld_lds16(const void* g, void* l) {
    __builtin_amdgcn_global_load_lds(
        (const __attribute__((address_space(1))) void*)g,
        (__attribute__((address_space(3))) void*)l, 16, 0, 0);
}

// ---------------------------------------------------------------- fp32 -> bf16
__global__ __launch_bounds__(256) void f2b_kernel(const float* __restrict__ s,
                                                  __hip_bfloat16* __restrict__ d,
                                                  int n) {
    int i = (blockIdx.x * 256 + threadIdx.x) * 4;
    if (i < n) {
        float4 v = *(const float4*)&s[i];
        d[i + 0] = __float2bfloat16(v.x);
        d[i + 1] = __float2bfloat16(v.y);
        d[i + 2] = __float2bfloat16(v.z);
        d[i + 3] = __float2bfloat16(v.w);
    }
}

// ---------------------------------------------------------------- NT GEMM
// C[m][n] = sum_k A[m][k] * Bw[n][k]  (+bias[n]), m97-style 128x128 tile, BK=32.
// MODE 0: -> q bf16 [B,H,N,D], value=(acc+bias)*0.125
// MODE 1: -> k bf16 [B,H,N,D]
// MODE 2: -> vt bf16 [B,H,D,N]
// MODE 3: -> out fp32 [M][N]
template <int MODE>
__global__ __launch_bounds__(256) void gemm_nt(const __hip_bfloat16* __restrict__ A,
                                               const __hip_bfloat16* __restrict__ Bw,
                                               const float* __restrict__ bias,
                                               void* __restrict__ out,
                                               int M, int Nn, int K) {
    __shared__ __hip_bfloat16 Al[128 * 32];
    __shared__ __hip_bfloat16 Bl[128 * 32];
    const int t = threadIdx.x, w = t >> 6, l = t & 63;
    const int wr = w >> 1, wc = w & 1, lr = l & 15, lg = l >> 4;
    const int m0 = blockIdx.y * 128, n0 = blockIdx.x * 128;

    f32x4 acc[4][4] = {};

    for (int k0 = 0; k0 < K; k0 += 32) {
#pragma unroll
        for (int it = 0; it < 2; ++it) {
            int i = t + it * 256;
            int r = i >> 2, c8 = (i & 3) * 8;
            gld_lds16(A + (size_t)(m0 + r) * K + k0 + c8, &Al[i * 8]);
            gld_lds16(Bw + (size_t)(n0 + r) * K + k0 + c8, &Bl[i * 8]);
        }
        __syncthreads();
        bf16x8 af[4], bfr[4];
#pragma unroll
        for (int mi = 0; mi < 4; ++mi)
            af[mi] = *(const bf16x8*)&Al[(wr * 64 + mi * 16 + lr) * 32 + lg * 8];
#pragma unroll
        for (int ni = 0; ni < 4; ++ni)
            bfr[ni] = *(const bf16x8*)&Bl[(wc * 64 + ni * 16 + lr) * 32 + lg * 8];
#pragma unroll
        for (int mi = 0; mi < 4; ++mi)
#pragma unroll
            for (int ni = 0; ni < 4; ++ni)
                acc[mi][ni] = __builtin_amdgcn_mfma_f32_16x16x32_bf16(
                    af[mi], bfr[ni], acc[mi][ni], 0, 0, 0);
        __syncthreads();
    }

#pragma unroll
    for (int mi = 0; mi < 4; ++mi) {
#pragma unroll
        for (int ni = 0; ni < 4; ++ni) {
            int col = n0 + wc * 64 + ni * 16 + lr;
            float bb = bias[col];
#pragma unroll
            for (int j = 0; j < 4; ++j) {
                int row = m0 + wr * 64 + mi * 16 + lg * 4 + j;
                float v = acc[mi][ni][j] + bb;
                if constexpr (MODE == 3) {
                    ((float*)out)[(size_t)row * Nn + col] = v;
                } else {
                    int bb_ = row >> 10, nn = row & 1023;
                    int hh = col >> 6, dd = col & 63;
                    if constexpr (MODE == 0) {
                        v *= 0.125f;  // 1/sqrt(D)
                        ((__hip_bfloat16*)out)[(((size_t)bb_ * H_ + hh) * N_ + nn) * D_ + dd] =
                            __float2bfloat16(v);
                    } else if constexpr (MODE == 1) {
                        ((__hip_bfloat16*)out)[(((size_t)bb_ * H_ + hh) * N_ + nn) * D_ + dd] =
                            __float2bfloat16(v);
                    } else {
                        ((__hip_bfloat16*)out)[(((size_t)bb_ * H_ + hh) * D_ + dd) * N_ + nn] =
                            __float2bfloat16(v);
                    }
                }
            }
        }
    }
}

// ---------------------------------------------------------------- attention
// grid: B*H*(N/64) blocks. block = 256 threads = 4 waves, each wave owns 16 q rows.
__global__ __launch_bounds__(256) void attn_kernel(const __hip_bfloat16* __restrict__ q,
                                                   const __hip_bfloat16* __restrict__ k,
                                                   const __hip_bfloat16* __restrict__ vt,
                                                   const float* __restrict__ bias,
                                                   const int* __restrict__ mask,
                                                   __hip_bfloat16* __restrict__ ao) {
    const int blk = blockIdx.x;
    const int qt = blk & 15, h = (blk >> 4) & 15, b = blk >> 8;
    const int t = threadIdx.x, w = t >> 6, l = t & 63;
    const int lr = l & 15, lg = l >> 4;

    __shared__ __hip_bfloat16 Kl[64][72];   // keys x d, +8 pad (144B stride -> 2-way only)
    __shared__ __hip_bfloat16 Vl[64][72];   // d x keys (V^T), +8 pad
    __shared__ __hip_bfloat16 Pl[4][16][72];  // per-wave P relayout buffer

    const int qr0 = qt * 64;
    const size_t bh = (size_t)b * H_ + h;
    const int qrow_base = qr0 + w * 16 + lg * 4;

    // Q fragments, kept in registers for the whole K loop
    bf16x8 qf[2];
#pragma unroll
    for (int half = 0; half < 2; ++half)
        qf[half] = *(const bf16x8*)&q[(bh * N_ + qr0 + w * 16 + lr) * D_ + half * 32 + lg * 8];

    f32x4 acc[4] = {};
    float m_[4], l_[4];
#pragma unroll
    for (int j = 0; j < 4; ++j) { m_[j] = -3e38f; l_[j] = 0.f; }

    for (int kt = 0; kt < 16; ++kt) {
        // stage K tile and V^T tile (16B vector copies)
#pragma unroll
        for (int it = 0; it < 2; ++it) {
            int i = t + it * 256;
            int r = i >> 3, c = (i & 7) * 8;
            *(uint4*)&Kl[r][c] = *(const uint4*)&k[(bh * N_ + kt * 64 + r) * D_ + c];
            *(uint4*)&Vl[r][c] = *(const uint4*)&vt[(bh * D_ + r) * N_ + kt * 64 + c];
        }
        __syncthreads();

        // S = Q K^T  (16x64 per wave)
        f32x4 s[4];
#pragma unroll
        for (int nkb = 0; nkb < 4; ++nkb) {
            f32x4 a = {};
#pragma unroll
            for (int half = 0; half < 2; ++half) {
                bf16x8 kf = *(const bf16x8*)&Kl[nkb * 16 + lr][half * 32 + lg * 8];
                a = __builtin_amdgcn_mfma_f32_16x16x32_bf16(qf[half], kf, a, 0, 0, 0);
            }
            s[nkb] = a;
        }

        // bias + mask (fp32)
#pragma unroll
        for (int nkb = 0; nkb < 4; ++nkb) {
            int key = kt * 64 + nkb * 16 + lr;
            int mk = mask[b * N_ + key];
#pragma unroll
            for (int j = 0; j < 4; ++j) {
                float bb = bias[(bh * N_ + qrow_base + j) * N_ + key];
                s[nkb][j] = mk ? (s[nkb][j] + bb) : -1e30f;
            }
        }

        // online softmax: rows live on 16-lane groups -> shfl_xor {1,2,4,8}
        float al[4];
#pragma unroll
        for (int j = 0; j < 4; ++j) {
            float tm = fmaxf(fmaxf(s[0][j], s[1][j]), fmaxf(s[2][j], s[3][j]));
            tm = fmaxf(tm, __shfl_xor(tm, 1));
            tm = fmaxf(tm, __shfl_xor(tm, 2));
            tm = fmaxf(tm, __shfl_xor(tm, 4));
            tm = fmaxf(tm, __shfl_xor(tm, 8));
            float mn = fmaxf(m_[j], tm);
            al[j] = __expf(m_[j] - mn);
            m_[j] = mn;
            float ts = 0.f;
#pragma unroll
            for (int nkb = 0; nkb < 4; ++nkb) {
                float p = __expf(s[nkb][j] - mn);
                s[nkb][j] = p;
                ts += p;
            }
            ts += __shfl_xor(ts, 1);
            ts += __shfl_xor(ts, 2);
            ts += __shfl_xor(ts, 4);
            ts += __shfl_xor(ts, 8);
            l_[j] = l_[j] * al[j] + ts;
        }

        // P -> LDS (wave-private) to re-shape C-layout -> A-operand layout
#pragma unroll
        for (int nkb = 0; nkb < 4; ++nkb)
#pragma unroll
            for (int j = 0; j < 4; ++j)
                Pl[w][lg * 4 + j][nkb * 16 + lr] = __float2bfloat16(s[nkb][j]);

        // rescale accumulator
#pragma unroll
        for (int db = 0; db < 4; ++db)
#pragma unroll
            for (int j = 0; j < 4; ++j)
                acc[db][j] *= al[j];

        // O += P V
#pragma unroll
        for (int db = 0; db < 4; ++db) {
#pragma unroll
            for (int mh = 0; mh < 2; ++mh) {
                bf16x8 pf = *(const bf16x8*)&Pl[w][lr][mh * 32 + lg * 8];
                bf16x8 vf = *(const bf16x8*)&Vl[db * 16 + lr][mh * 32 + lg * 8];
                acc[db] = __builtin_amdgcn_mfma_f32_16x16x32_bf16(pf, vf, acc[db], 0, 0, 0);
            }
        }
        __syncthreads();
    }

    // epilogue: ao bf16 [B,N,C] with c = h*64 + d
#pragma unroll
    for (int db = 0; db < 4; ++db)
#pragma unroll
        for (int j = 0; j < 4; ++j) {
            float o = acc[db][j] / l_[j];
            ao[((size_t)b * N_ + qrow_base + j) * C_ + h * 64 + db * 16 + lr] =
                __float2bfloat16(o);
        }
}

// ---------------------------------------------------------------- launcher
extern "C" void kernel_launch(void* const* d_in, const int* in_sizes, int n_in,
                              void* d_out, int out_size, void* d_ws, size_t ws_size,
                              hipStream_t stream) {
    const float* x    = (const float*)d_in[0];
    const float* bias = (const float*)d_in[1];
    const int*   mask = (const int*)d_in[2];
    const float* Wq   = (const float*)d_in[3];
    const float* bq   = (const float*)d_in[4];
    const float* Wk   = (const float*)d_in[5];
    const float* bk   = (const float*)d_in[6];
    const float* Wv   = (const float*)d_in[7];
    const float* bv   = (const float*)d_in[8];
    const float* Wo   = (const float*)d_in[9];
    const float* bo   = (const float*)d_in[10];
    float* out = (float*)d_out;

    char* ws = (char*)d_ws;
    const size_t MB = 1u << 20;
    __hip_bfloat16* xb  = (__hip_bfloat16*)(ws + 0 * MB);   // 8 MB
    __hip_bfloat16* wqb = (__hip_bfloat16*)(ws + 8 * MB);   // 2 MB
    __hip_bfloat16* wkb = (__hip_bfloat16*)(ws + 10 * MB);
    __hip_bfloat16* wvb = (__hip_bfloat16*)(ws + 12 * MB);
    __hip_bfloat16* wob = (__hip_bfloat16*)(ws + 14 * MB);
    __hip_bfloat16* qb  = (__hip_bfloat16*)(ws + 16 * MB);  // 8 MB
    __hip_bfloat16* kb  = (__hip_bfloat16*)(ws + 24 * MB);  // 8 MB
    __hip_bfloat16* vtb = (__hip_bfloat16*)(ws + 32 * MB);  // 8 MB
    __hip_bfloat16* aob = (__hip_bfloat16*)(ws + 40 * MB);  // 8 MB

    // fp32 -> bf16
    f2b_kernel<<<4096, 256, 0, stream>>>(x, xb, B_ * N_ * C_);
    f2b_kernel<<<1024, 256, 0, stream>>>(Wq, wqb, C_ * C_);
    f2b_kernel<<<1024, 256, 0, stream>>>(Wk, wkb, C_ * C_);
    f2b_kernel<<<1024, 256, 0, stream>>>(Wv, wvb, C_ * C_);
    f2b_kernel<<<1024, 256, 0, stream>>>(Wo, wob, C_ * C_);

    dim3 g(C_ / 128, (B_ * N_) / 128);  // (8, 32)
    gemm_nt<0><<<g, 256, 0, stream>>>(xb, wqb, bq, qb,  B_ * N_, C_, C_);
    gemm_nt<1><<<g, 256, 0, stream>>>(xb, wkb, bk, kb,  B_ * N_, C_, C_);
    gemm_nt<2><<<g, 256, 0, stream>>>(xb, wvb, bv, vtb, B_ * N_, C_, C_);

    attn_kernel<<<B_ * H_ * (N_ / 64), 256, 0, stream>>>(qb, kb, vtb, bias, mask, aob);

    gemm_nt<3><<<g, 256, 0, stream>>>(aob, wob, bo, out, B_ * N_, C_, C_);
}

// Round 2
// 231.989 us; speedup vs baseline: 1.3058x; 1.3058x over previous
//
#include <hip/hip_runtime.h>
#include <hip/hip_bf16.h>

#define B_ 4
#define N_ 1024
#define C_ 1024
#define H_ 16
#define D_ 64

typedef __attribute__((ext_vector_type(8))) short bf16x8;
typedef __attribute__((ext_vector_type(4))) float f32x4;

__device__ __forceinline__ void gld_lds16(const void* g, void* l) {
    __builtin_amdgcn_global_load_lds(
        (const __attribute__((address_space(1))) void*)g,
        (__attribute__((address_space(3))) void*)l, 16, 0, 0);
}

// ---------------------------------------------------------------- fp32 -> bf16
__global__ __launch_bounds__(256) void f2b_kernel(const float* __restrict__ s,
                                                  __hip_bfloat16* __restrict__ d,
                                                  int n) {
    int i = (blockIdx.x * 256 + threadIdx.x) * 4;
    if (i < n) {
        float4 v = *(const float4*)&s[i];
        d[i + 0] = __float2bfloat16(v.x);
        d[i + 1] = __float2bfloat16(v.y);
        d[i + 2] = __float2bfloat16(v.z);
        d[i + 3] = __float2bfloat16(v.w);
    }
}

// 4 weight matrices in one dispatch (blockIdx.y selects)
__global__ __launch_bounds__(256) void f2b4_kernel(const float* __restrict__ w0,
                                                   const float* __restrict__ w1,
                                                   const float* __restrict__ w2,
                                                   const float* __restrict__ w3,
                                                   __hip_bfloat16* __restrict__ d0,
                                                   __hip_bfloat16* __restrict__ d1,
                                                   __hip_bfloat16* __restrict__ d2,
                                                   __hip_bfloat16* __restrict__ d3) {
    int sel = blockIdx.y;
    const float* s = sel == 0 ? w0 : sel == 1 ? w1 : sel == 2 ? w2 : w3;
    __hip_bfloat16* d = sel == 0 ? d0 : sel == 1 ? d1 : sel == 2 ? d2 : d3;
    int i = (blockIdx.x * 256 + threadIdx.x) * 4;
    float4 v = *(const float4*)&s[i];
    d[i + 0] = __float2bfloat16(v.x);
    d[i + 1] = __float2bfloat16(v.y);
    d[i + 2] = __float2bfloat16(v.z);
    d[i + 3] = __float2bfloat16(v.w);
}

// ---------------------------------------------------------------- fused QKV GEMM
// C[m][n] = sum_k X[m][k] * W[n][k] + bias[n]; 128x128 tile, BK=32.
// blockIdx.x: [0,8)->Q (scaled, [B,H,N,D]), [8,16)->K ([B,H,N,D]), [16,24)->V^T ([B,H,D,N])
__global__ __launch_bounds__(256) void gemm_qkv(const __hip_bfloat16* __restrict__ A,
                                                const __hip_bfloat16* __restrict__ wq,
                                                const __hip_bfloat16* __restrict__ wk,
                                                const __hip_bfloat16* __restrict__ wv,
                                                const float* __restrict__ bq,
                                                const float* __restrict__ bk,
                                                const float* __restrict__ bv,
                                                __hip_bfloat16* __restrict__ qo,
                                                __hip_bfloat16* __restrict__ ko,
                                                __hip_bfloat16* __restrict__ vto) {
    __shared__ __hip_bfloat16 Al[128 * 32];
    __shared__ __hip_bfloat16 Bl[128 * 32];
    const int sel = blockIdx.x >> 3;
    const __hip_bfloat16* Bw = sel == 0 ? wq : sel == 1 ? wk : wv;
    const float* bias = sel == 0 ? bq : sel == 1 ? bk : bv;
    const int t = threadIdx.x, w = t >> 6, l = t & 63;
    const int wr = w >> 1, wc = w & 1, lr = l & 15, lg = l >> 4;
    const int m0 = blockIdx.y * 128, n0 = (blockIdx.x & 7) * 128;
    const int K = C_;

    f32x4 acc[4][4] = {};

    for (int k0 = 0; k0 < K; k0 += 32) {
#pragma unroll
        for (int it = 0; it < 2; ++it) {
            int i = t + it * 256;
            int r = i >> 2, c8 = (i & 3) * 8;
            gld_lds16(A + (size_t)(m0 + r) * K + k0 + c8, &Al[i * 8]);
            gld_lds16(Bw + (size_t)(n0 + r) * K + k0 + c8, &Bl[i * 8]);
        }
        __syncthreads();
        bf16x8 af[4], bfr[4];
#pragma unroll
        for (int mi = 0; mi < 4; ++mi)
            af[mi] = *(const bf16x8*)&Al[(wr * 64 + mi * 16 + lr) * 32 + lg * 8];
#pragma unroll
        for (int ni = 0; ni < 4; ++ni)
            bfr[ni] = *(const bf16x8*)&Bl[(wc * 64 + ni * 16 + lr) * 32 + lg * 8];
#pragma unroll
        for (int mi = 0; mi < 4; ++mi)
#pragma unroll
            for (int ni = 0; ni < 4; ++ni)
                acc[mi][ni] = __builtin_amdgcn_mfma_f32_16x16x32_bf16(
                    af[mi], bfr[ni], acc[mi][ni], 0, 0, 0);
        __syncthreads();
    }

#pragma unroll
    for (int mi = 0; mi < 4; ++mi) {
#pragma unroll
        for (int ni = 0; ni < 4; ++ni) {
            int col = n0 + wc * 64 + ni * 16 + lr;
            float bb = bias[col];
#pragma unroll
            for (int j = 0; j < 4; ++j) {
                int row = m0 + wr * 64 + mi * 16 + lg * 4 + j;
                float v = acc[mi][ni][j] + bb;
                int bb_ = row >> 10, nn = row & 1023;
                int hh = col >> 6, dd = col & 63;
                if (sel == 0) {
                    qo[(((size_t)bb_ * H_ + hh) * N_ + nn) * D_ + dd] =
                        __float2bfloat16(v * 0.125f);
                } else if (sel == 1) {
                    ko[(((size_t)bb_ * H_ + hh) * N_ + nn) * D_ + dd] =
                        __float2bfloat16(v);
                } else {
                    vto[(((size_t)bb_ * H_ + hh) * D_ + dd) * N_ + nn] =
                        __float2bfloat16(v);
                }
            }
        }
    }
}

// ---------------------------------------------------------------- output proj GEMM
__global__ __launch_bounds__(256) void gemm_out(const __hip_bfloat16* __restrict__ A,
                                                const __hip_bfloat16* __restrict__ Bw,
                                                const float* __restrict__ bias,
                                                float* __restrict__ out) {
    __shared__ __hip_bfloat16 Al[128 * 32];
    __shared__ __hip_bfloat16 Bl[128 * 32];
    const int t = threadIdx.x, w = t >> 6, l = t & 63;
    const int wr = w >> 1, wc = w & 1, lr = l & 15, lg = l >> 4;
    const int m0 = blockIdx.y * 128, n0 = blockIdx.x * 128;
    const int K = C_;

    f32x4 acc[4][4] = {};

    for (int k0 = 0; k0 < K; k0 += 32) {
#pragma unroll
        for (int it = 0; it < 2; ++it) {
            int i = t + it * 256;
            int r = i >> 2, c8 = (i & 3) * 8;
            gld_lds16(A + (size_t)(m0 + r) * K + k0 + c8, &Al[i * 8]);
            gld_lds16(Bw + (size_t)(n0 + r) * K + k0 + c8, &Bl[i * 8]);
        }
        __syncthreads();
        bf16x8 af[4], bfr[4];
#pragma unroll
        for (int mi = 0; mi < 4; ++mi)
            af[mi] = *(const bf16x8*)&Al[(wr * 64 + mi * 16 + lr) * 32 + lg * 8];
#pragma unroll
        for (int ni = 0; ni < 4; ++ni)
            bfr[ni] = *(const bf16x8*)&Bl[(wc * 64 + ni * 16 + lr) * 32 + lg * 8];
#pragma unroll
        for (int mi = 0; mi < 4; ++mi)
#pragma unroll
            for (int ni = 0; ni < 4; ++ni)
                acc[mi][ni] = __builtin_amdgcn_mfma_f32_16x16x32_bf16(
                    af[mi], bfr[ni], acc[mi][ni], 0, 0, 0);
        __syncthreads();
    }

#pragma unroll
    for (int mi = 0; mi < 4; ++mi)
#pragma unroll
        for (int ni = 0; ni < 4; ++ni) {
            int col = n0 + wc * 64 + ni * 16 + lr;
            float bb = bias[col];
#pragma unroll
            for (int j = 0; j < 4; ++j) {
                int row = m0 + wr * 64 + mi * 16 + lg * 4 + j;
                out[(size_t)row * C_ + col] = acc[mi][ni][j] + bb;
            }
        }
}

// ---------------------------------------------------------------- attention
// Swapped-operand flash attention. grid 1024 (XCD-swizzled), 4 waves/block,
// wave = 16 q rows, barrier-free (P relayout LDS is wave-private).
// Per tile (64 keys): K/V frags straight from global (L2-resident),
// bias prefetched 1 tile ahead as float4.
__global__ __launch_bounds__(256) void attn_kernel(const __hip_bfloat16* __restrict__ q,
                                                   const __hip_bfloat16* __restrict__ k,
                                                   const __hip_bfloat16* __restrict__ vt,
                                                   const float* __restrict__ bias,
                                                   const int* __restrict__ mask,
                                                   __hip_bfloat16* __restrict__ ao) {
    const int orig = blockIdx.x;
    const int wg = (orig & 7) * 128 + (orig >> 3);  // bijective XCD swizzle (1024 % 8 == 0)
    const int qt = wg & 15, h = (wg >> 4) & 15, b = wg >> 8;
    const int t = threadIdx.x, w = t >> 6, l = t & 63;
    const int lr = l & 15, lg = l >> 4;

    __shared__ __hip_bfloat16 Pl[4][16][72];  // per-wave P buffer, 144B stride (2-way only)

    const size_t bh = (size_t)b * H_ + h;
    const int qr0 = qt * 64;
    const int myrow = qr0 + w * 16 + lr;          // this lane's q row (S^T col)
    const int orow_base = qr0 + w * 16 + lg * 4;  // acc rows

    // Q fragment (B-operand of swapped QK^T): lane holds Q[myrow][d = lg*8+j]
    bf16x8 qf[2];
#pragma unroll
    for (int half = 0; half < 2; ++half)
        qf[half] = *(const bf16x8*)&q[(bh * N_ + myrow) * D_ + half * 32 + lg * 8];

    const float* brow = bias + ((size_t)bh * N_ + myrow) * N_;
    const int* mrow = mask + (size_t)b * N_;

    f32x4 acc[4] = {};
    float m_ = -3e38f, l_ = 0.f;

    // prologue: bias for tile 0
    f32x4 bpf[4];
#pragma unroll
    for (int nkb = 0; nkb < 4; ++nkb)
        bpf[nkb] = *(const f32x4*)&brow[nkb * 16 + lg * 4];

    for (int kt = 0; kt < 16; ++kt) {
        // K fragments (A-operand): row = key, k = d
        bf16x8 kf[4][2];
#pragma unroll
        for (int nkb = 0; nkb < 4; ++nkb)
#pragma unroll
            for (int half = 0; half < 2; ++half)
                kf[nkb][half] = *(const bf16x8*)
                    &k[(bh * N_ + kt * 64 + nkb * 16 + lr) * D_ + half * 32 + lg * 8];
        // V^T fragments (B-operand of PV): col = d, k = key
        bf16x8 vf[4][2];
#pragma unroll
        for (int db = 0; db < 4; ++db)
#pragma unroll
            for (int mh = 0; mh < 2; ++mh)
                vf[db][mh] = *(const bf16x8*)
                    &vt[(bh * D_ + db * 16 + lr) * N_ + kt * 64 + mh * 32 + lg * 8];

        int4 mk[4];
#pragma unroll
        for (int nkb = 0; nkb < 4; ++nkb)
            mk[nkb] = *(const int4*)&mrow[kt * 64 + nkb * 16 + lg * 4];

        // prefetch next tile's bias (issued after K/V -> K-wait leaves these in flight)
        const int ktn = kt < 15 ? kt + 1 : 15;
        f32x4 bnx[4];
#pragma unroll
        for (int nkb = 0; nkb < 4; ++nkb)
            bnx[nkb] = *(const f32x4*)&brow[ktn * 64 + nkb * 16 + lg * 4];

        // S^T tile: lane holds S[key = nkb*16+lg*4+j][qrow = myrow]
        float s[4][4];
#pragma unroll
        for (int nkb = 0; nkb < 4; ++nkb) {
            f32x4 a = {};
#pragma unroll
            for (int half = 0; half < 2; ++half)
                a = __builtin_amdgcn_mfma_f32_16x16x32_bf16(kf[nkb][half], qf[half], a, 0, 0, 0);
#pragma unroll
            for (int j = 0; j < 4; ++j) s[nkb][j] = a[j];
        }

        // bias + mask (bias was prefetched last iteration)
#pragma unroll
        for (int nkb = 0; nkb < 4; ++nkb) {
            int mks[4] = {mk[nkb].x, mk[nkb].y, mk[nkb].z, mk[nkb].w};
#pragma unroll
            for (int j = 0; j < 4; ++j)
                s[nkb][j] = mks[j] ? s[nkb][j] + bpf[nkb][j] : -1e30f;
        }

        // online softmax: all 16 values of row `myrow` are lane-local;
        // cross-lane only over lg groups (xor 16, 32)
        float tm = s[0][0];
#pragma unroll
        for (int nkb = 0; nkb < 4; ++nkb)
#pragma unroll
            for (int j = 0; j < 4; ++j) tm = fmaxf(tm, s[nkb][j]);
        tm = fmaxf(tm, __shfl_xor(tm, 16));
        tm = fmaxf(tm, __shfl_xor(tm, 32));
        const float mn = fmaxf(m_, tm);
        const float al = __expf(m_ - mn);
        m_ = mn;
        float ts = 0.f;
#pragma unroll
        for (int nkb = 0; nkb < 4; ++nkb)
#pragma unroll
            for (int j = 0; j < 4; ++j) {
                float p = __expf(s[nkb][j] - mn);
                s[nkb][j] = p;
                ts += p;
            }
        ts += __shfl_xor(ts, 16);
        ts += __shfl_xor(ts, 32);
        l_ = l_ * al + ts;

        // P -> wave-private LDS: row = myrow(lr), 4 consecutive keys per ds_write_b64
#pragma unroll
        for (int nkb = 0; nkb < 4; ++nkb) {
            __hip_bfloat16 pk[4];
#pragma unroll
            for (int j = 0; j < 4; ++j) pk[j] = __float2bfloat16(s[nkb][j]);
            *(short4*)&Pl[w][lr][nkb * 16 + lg * 4] = *(const short4*)pk;
        }

        // rescale acc (rows lg*4+j) by that row's al (lives on lane lr = row)
        float alr[4];
#pragma unroll
        for (int j = 0; j < 4; ++j) alr[j] = __shfl(al, lg * 4 + j);
#pragma unroll
        for (int db = 0; db < 4; ++db)
#pragma unroll
            for (int j = 0; j < 4; ++j) acc[db][j] *= alr[j];

        // O += P V : A-frag from LDS, B-frag = vf
        bf16x8 paf[2];
#pragma unroll
        for (int mh = 0; mh < 2; ++mh)
            paf[mh] = *(const bf16x8*)&Pl[w][lr][mh * 32 + lg * 8];
#pragma unroll
        for (int db = 0; db < 4; ++db)
#pragma unroll
            for (int mh = 0; mh < 2; ++mh)
                acc[db] = __builtin_amdgcn_mfma_f32_16x16x32_bf16(paf[mh], vf[db][mh],
                                                                  acc[db], 0, 0, 0);

#pragma unroll
        for (int nkb = 0; nkb < 4; ++nkb) bpf[nkb] = bnx[nkb];
    }

    // epilogue: acc[db][j] = O[orow_base+j][d = db*16+lr], divide by row sum
    float linv[4];
#pragma unroll
    for (int j = 0; j < 4; ++j) linv[j] = 1.f / __shfl(l_, lg * 4 + j);
#pragma unroll
    for (int db = 0; db < 4; ++db)
#pragma unroll
        for (int j = 0; j < 4; ++j)
            ao[((size_t)b * N_ + orow_base + j) * C_ + h * 64 + db * 16 + lr] =
                __float2bfloat16(acc[db][j] * linv[j]);
}

// ---------------------------------------------------------------- launcher
extern "C" void kernel_launch(void* const* d_in, const int* in_sizes, int n_in,
                              void* d_out, int out_size, void* d_ws, size_t ws_size,
                              hipStream_t stream) {
    const float* x    = (const float*)d_in[0];
    const float* bias = (const float*)d_in[1];
    const int*   mask = (const int*)d_in[2];
    const float* Wq   = (const float*)d_in[3];
    const float* bq   = (const float*)d_in[4];
    const float* Wk   = (const float*)d_in[5];
    const float* bk   = (const float*)d_in[6];
    const float* Wv   = (const float*)d_in[7];
    const float* bv   = (const float*)d_in[8];
    const float* Wo   = (const float*)d_in[9];
    const float* bo   = (const float*)d_in[10];
    float* out = (float*)d_out;

    char* ws = (char*)d_ws;
    const size_t MB = 1u << 20;
    __hip_bfloat16* xb  = (__hip_bfloat16*)(ws + 0 * MB);   // 8 MB
    __hip_bfloat16* wqb = (__hip_bfloat16*)(ws + 8 * MB);   // 2 MB each
    __hip_bfloat16* wkb = (__hip_bfloat16*)(ws + 10 * MB);
    __hip_bfloat16* wvb = (__hip_bfloat16*)(ws + 12 * MB);
    __hip_bfloat16* wob = (__hip_bfloat16*)(ws + 14 * MB);
    __hip_bfloat16* qb  = (__hip_bfloat16*)(ws + 16 * MB);  // 8 MB
    __hip_bfloat16* kb  = (__hip_bfloat16*)(ws + 24 * MB);  // 8 MB
    __hip_bfloat16* vtb = (__hip_bfloat16*)(ws + 32 * MB);  // 8 MB
    __hip_bfloat16* aob = (__hip_bfloat16*)(ws + 40 * MB);  // 8 MB

    f2b_kernel<<<4096, 256, 0, stream>>>(x, xb, B_ * N_ * C_);
    f2b4_kernel<<<dim3(1024, 4), 256, 0, stream>>>(Wq, Wk, Wv, Wo, wqb, wkb, wvb, wob);

    gemm_qkv<<<dim3(24, 32), 256, 0, stream>>>(xb, wqb, wkb, wvb, bq, bk, bv, qb, kb, vtb);

    attn_kernel<<<B_ * H_ * (N_ / 64), 256, 0, stream>>>(qb, kb, vtb, bias, mask, aob);

    gemm_out<<<dim3(8, 32), 256, 0, stream>>>(aob, wob, bo, out);
}

// Round 4
// 171.297 us; speedup vs baseline: 1.7684x; 1.3543x over previous
//
#include <hip/hip_runtime.h>
#include <hip/hip_bf16.h>

#define B_ 4
#define N_ 1024
#define C_ 1024
#define H_ 16
#define D_ 64

typedef __attribute__((ext_vector_type(8))) short bf16x8;
typedef __attribute__((ext_vector_type(4))) float f32x4;

__device__ __forceinline__ void gld_lds16(const void* g, void* l) {
    __builtin_amdgcn_global_load_lds(
        (const __attribute__((address_space(1))) void*)g,
        (__attribute__((address_space(3))) void*)l, 16, 0, 0);
}

// ---------------------------------------------------------------- fp32 -> bf16
__global__ __launch_bounds__(256) void f2b_kernel(const float* __restrict__ s,
                                                  __hip_bfloat16* __restrict__ d,
                                                  int n) {
    int i = (blockIdx.x * 256 + threadIdx.x) * 4;
    if (i < n) {
        float4 v = *(const float4*)&s[i];
        d[i + 0] = __float2bfloat16(v.x);
        d[i + 1] = __float2bfloat16(v.y);
        d[i + 2] = __float2bfloat16(v.z);
        d[i + 3] = __float2bfloat16(v.w);
    }
}

// 4 weight matrices in one dispatch (blockIdx.y selects)
__global__ __launch_bounds__(256) void f2b4_kernel(const float* __restrict__ w0,
                                                   const float* __restrict__ w1,
                                                   const float* __restrict__ w2,
                                                   const float* __restrict__ w3,
                                                   __hip_bfloat16* __restrict__ d0,
                                                   __hip_bfloat16* __restrict__ d1,
                                                   __hip_bfloat16* __restrict__ d2,
                                                   __hip_bfloat16* __restrict__ d3) {
    int sel = blockIdx.y;
    const float* s = sel == 0 ? w0 : sel == 1 ? w1 : sel == 2 ? w2 : w3;
    __hip_bfloat16* d = sel == 0 ? d0 : sel == 1 ? d1 : sel == 2 ? d2 : d3;
    int i = (blockIdx.x * 256 + threadIdx.x) * 4;
    float4 v = *(const float4*)&s[i];
    d[i + 0] = __float2bfloat16(v.x);
    d[i + 1] = __float2bfloat16(v.y);
    d[i + 2] = __float2bfloat16(v.z);
    d[i + 3] = __float2bfloat16(v.w);
}

// ---------------------------------------------------------------- fused QKV GEMM
__global__ __launch_bounds__(256) void gemm_qkv(const __hip_bfloat16* __restrict__ A,
                                                const __hip_bfloat16* __restrict__ wq,
                                                const __hip_bfloat16* __restrict__ wk,
                                                const __hip_bfloat16* __restrict__ wv,
                                                const float* __restrict__ bq,
                                                const float* __restrict__ bk,
                                                const float* __restrict__ bv,
                                                __hip_bfloat16* __restrict__ qo,
                                                __hip_bfloat16* __restrict__ ko,
                                                __hip_bfloat16* __restrict__ vto) {
    __shared__ __hip_bfloat16 Al[128 * 32];
    __shared__ __hip_bfloat16 Bl[128 * 32];
    const int sel = blockIdx.x >> 3;
    const __hip_bfloat16* Bw = sel == 0 ? wq : sel == 1 ? wk : wv;
    const float* bias = sel == 0 ? bq : sel == 1 ? bk : bv;
    const int t = threadIdx.x, w = t >> 6, l = t & 63;
    const int wr = w >> 1, wc = w & 1, lr = l & 15, lg = l >> 4;
    const int m0 = blockIdx.y * 128, n0 = (blockIdx.x & 7) * 128;
    const int K = C_;

    f32x4 acc[4][4] = {};

    for (int k0 = 0; k0 < K; k0 += 32) {
#pragma unroll
        for (int it = 0; it < 2; ++it) {
            int i = t + it * 256;
            int r = i >> 2, c8 = (i & 3) * 8;
            gld_lds16(A + (size_t)(m0 + r) * K + k0 + c8, &Al[i * 8]);
            gld_lds16(Bw + (size_t)(n0 + r) * K + k0 + c8, &Bl[i * 8]);
        }
        __syncthreads();
        bf16x8 af[4], bfr[4];
#pragma unroll
        for (int mi = 0; mi < 4; ++mi)
            af[mi] = *(const bf16x8*)&Al[(wr * 64 + mi * 16 + lr) * 32 + lg * 8];
#pragma unroll
        for (int ni = 0; ni < 4; ++ni)
            bfr[ni] = *(const bf16x8*)&Bl[(wc * 64 + ni * 16 + lr) * 32 + lg * 8];
#pragma unroll
        for (int mi = 0; mi < 4; ++mi)
#pragma unroll
            for (int ni = 0; ni < 4; ++ni)
                acc[mi][ni] = __builtin_amdgcn_mfma_f32_16x16x32_bf16(
                    af[mi], bfr[ni], acc[mi][ni], 0, 0, 0);
        __syncthreads();
    }

#pragma unroll
    for (int mi = 0; mi < 4; ++mi) {
#pragma unroll
        for (int ni = 0; ni < 4; ++ni) {
            int col = n0 + wc * 64 + ni * 16 + lr;
            float bb = bias[col];
#pragma unroll
            for (int j = 0; j < 4; ++j) {
                int row = m0 + wr * 64 + mi * 16 + lg * 4 + j;
                float v = acc[mi][ni][j] + bb;
                int bb_ = row >> 10, nn = row & 1023;
                int hh = col >> 6, dd = col & 63;
                if (sel == 0) {
                    qo[(((size_t)bb_ * H_ + hh) * N_ + nn) * D_ + dd] =
                        __float2bfloat16(v * 0.125f);
                } else if (sel == 1) {
                    ko[(((size_t)bb_ * H_ + hh) * N_ + nn) * D_ + dd] =
                        __float2bfloat16(v);
                } else {
                    vto[(((size_t)bb_ * H_ + hh) * D_ + dd) * N_ + nn] =
                        __float2bfloat16(v);
                }
            }
        }
    }
}

// ---------------------------------------------------------------- output proj GEMM
__global__ __launch_bounds__(256) void gemm_out(const __hip_bfloat16* __restrict__ A,
                                                const __hip_bfloat16* __restrict__ Bw,
                                                const float* __restrict__ bias,
                                                float* __restrict__ out) {
    __shared__ __hip_bfloat16 Al[128 * 32];
    __shared__ __hip_bfloat16 Bl[128 * 32];
    const int t = threadIdx.x, w = t >> 6, l = t & 63;
    const int wr = w >> 1, wc = w & 1, lr = l & 15, lg = l >> 4;
    const int m0 = blockIdx.y * 128, n0 = blockIdx.x * 128;
    const int K = C_;

    f32x4 acc[4][4] = {};

    for (int k0 = 0; k0 < K; k0 += 32) {
#pragma unroll
        for (int it = 0; it < 2; ++it) {
            int i = t + it * 256;
            int r = i >> 2, c8 = (i & 3) * 8;
            gld_lds16(A + (size_t)(m0 + r) * K + k0 + c8, &Al[i * 8]);
            gld_lds16(Bw + (size_t)(n0 + r) * K + k0 + c8, &Bl[i * 8]);
        }
        __syncthreads();
        bf16x8 af[4], bfr[4];
#pragma unroll
        for (int mi = 0; mi < 4; ++mi)
            af[mi] = *(const bf16x8*)&Al[(wr * 64 + mi * 16 + lr) * 32 + lg * 8];
#pragma unroll
        for (int ni = 0; ni < 4; ++ni)
            bfr[ni] = *(const bf16x8*)&Bl[(wc * 64 + ni * 16 + lr) * 32 + lg * 8];
#pragma unroll
        for (int mi = 0; mi < 4; ++mi)
#pragma unroll
            for (int ni = 0; ni < 4; ++ni)
                acc[mi][ni] = __builtin_amdgcn_mfma_f32_16x16x32_bf16(
                    af[mi], bfr[ni], acc[mi][ni], 0, 0, 0);
        __syncthreads();
    }

#pragma unroll
    for (int mi = 0; mi < 4; ++mi)
#pragma unroll
        for (int ni = 0; ni < 4; ++ni) {
            int col = n0 + wc * 64 + ni * 16 + lr;
            float bb = bias[col];
#pragma unroll
            for (int j = 0; j < 4; ++j) {
                int row = m0 + wr * 64 + mi * 16 + lg * 4 + j;
                out[(size_t)row * C_ + col] = acc[mi][ni][j] + bb;
            }
        }
}

// ---------------------------------------------------------------- attention
// Pipelined flash attention, race-free schedule:
//   s1: stage K(kt+1)+V(kt+1) -> buf[(kt+1)&1]   (4 gld_lds)
//   s2: issue bias(kt+1) raw  (4 dwordx4; penalty add deferred)
//   s3: vmcnt(8)  -- forces KV(kt)+bias(kt) complete, leaves the 8 new ops in flight
//   s4: s_barrier -- publishes KV(kt) LDS writes to all waves
//   s5-s7: QK^T + bias + pen, softmax, PV (all ds_reads consumed by MFMA here)
//   s9: s_barrier -- all reads of buf[kt&1] done before next iter overwrites it
// LDS tiles linear with XOR swizzle (elem ^= (row&7)<<3) applied on BOTH the
// pre-swizzled global source addrs and the ds_read indices.
__global__ __launch_bounds__(256) void attn_kernel(const __hip_bfloat16* __restrict__ q,
                                                   const __hip_bfloat16* __restrict__ k,
                                                   const __hip_bfloat16* __restrict__ vt,
                                                   const float* __restrict__ bias,
                                                   const int* __restrict__ mask,
                                                   __hip_bfloat16* __restrict__ ao) {
    const int orig = blockIdx.x;
    const int wg = (orig & 7) * 128 + (orig >> 3);  // bijective XCD swizzle
    const int qt = wg & 15, h = (wg >> 4) & 15, b = wg >> 8;
    const int t = threadIdx.x, w = t >> 6, l = t & 63;
    const int lr = l & 15, lg = l >> 4;

    __shared__ __hip_bfloat16 Kl[2][64 * 64];  // 16 KB double-buffered
    __shared__ __hip_bfloat16 Vl[2][64 * 64];  // 16 KB double-buffered
    __shared__ float Pen[1024];                // mask penalties, 4 KB
    __shared__ __hip_bfloat16 Pl[4][16][72];   // per-wave P buffer, 9.2 KB

    const size_t bh = (size_t)b * H_ + h;
    const int qr0 = qt * 64;
    const int myrow = qr0 + w * 16 + lr;
    const int orow_base = qr0 + w * 16 + lg * 4;

    // ---- mask -> additive penalties in LDS (one-time)
    {
        int4 mi = *(const int4*)&mask[b * N_ + t * 4];
        float4 p;
        p.x = mi.x ? 0.f : -1e30f;
        p.y = mi.y ? 0.f : -1e30f;
        p.z = mi.z ? 0.f : -1e30f;
        p.w = mi.w ? 0.f : -1e30f;
        *(float4*)&Pen[t * 4] = p;
    }
    __syncthreads();

    // ---- staging addresses. chunk c = it*256 + t; row = c>>3;
    // LDS slot (elems) = (c&7)*8; global col elem = slot ^ ((row&7)*8)
    const int c0 = t, c1 = t + 256;
    const int r0 = c0 >> 3, r1 = c1 >> 3;
    const int e0 = ((c0 & 7) * 8) ^ ((r0 & 7) << 3);
    const int e1 = ((c1 & 7) * 8) ^ ((r1 & 7) << 3);
    const __hip_bfloat16* kg0 = k + (bh * N_ + r0) * D_ + e0;
    const __hip_bfloat16* kg1 = k + (bh * N_ + r1) * D_ + e1;
    const __hip_bfloat16* vg0 = vt + (bh * D_ + r0) * N_ + e0;
    const __hip_bfloat16* vg1 = vt + (bh * D_ + r1) * N_ + e1;

    // ---- Q fragment (B-operand of swapped QK^T)
    bf16x8 qf[2];
#pragma unroll
    for (int half = 0; half < 2; ++half)
        qf[half] = *(const bf16x8*)&q[(bh * N_ + myrow) * D_ + half * 32 + lg * 8];

    const float* brow = bias + ((size_t)bh * N_ + myrow) * N_;
    const int swz = (lr & 7) << 3;

    f32x4 acc[4] = {};
    float m_ = -3e38f, l_ = 0.f;

    // ---- prologue: stage KV(0); issue bias(0) raw
    __builtin_amdgcn_sched_barrier(0);
    gld_lds16(kg0, &Kl[0][(w * 64) * 8]);
    gld_lds16(kg1, &Kl[0][(256 + w * 64) * 8]);
    gld_lds16(vg0, &Vl[0][(w * 64) * 8]);
    gld_lds16(vg1, &Vl[0][(256 + w * 64) * 8]);
    f32x4 bcur[4];
#pragma unroll
    for (int nkb = 0; nkb < 4; ++nkb)
        bcur[nkb] = *(const f32x4*)&brow[nkb * 16 + lg * 4];
    __builtin_amdgcn_sched_barrier(0);

#pragma unroll
    for (int kt = 0; kt < 16; ++kt) {
        const int ktn = kt < 15 ? kt + 1 : 15;  // clamped (keeps vmcnt uniform)

        // s1: stage KV(kt+1) into buf[(kt+1)&1]
        gld_lds16(kg0 + (size_t)ktn * 4096, &Kl[(kt + 1) & 1][(w * 64) * 8]);
        gld_lds16(kg1 + (size_t)ktn * 4096, &Kl[(kt + 1) & 1][(256 + w * 64) * 8]);
        gld_lds16(vg0 + ktn * 64, &Vl[(kt + 1) & 1][(w * 64) * 8]);
        gld_lds16(vg1 + ktn * 64, &Vl[(kt + 1) & 1][(256 + w * 64) * 8]);
        // s2: issue bias(kt+1) raw (no dependent use -> stays in flight)
        f32x4 bnxt[4];
#pragma unroll
        for (int nkb = 0; nkb < 4; ++nkb)
            bnxt[nkb] = *(const f32x4*)&brow[ktn * 64 + nkb * 16 + lg * 4];
        __builtin_amdgcn_sched_barrier(0);
        // s3: forces KV(kt) + bias(kt) landed (8 newest ops stay in flight)
        asm volatile("s_waitcnt vmcnt(8)" ::: "memory");
        __builtin_amdgcn_sched_barrier(0);
        // s4: publish KV(kt) to all waves
        __builtin_amdgcn_s_barrier();
        __builtin_amdgcn_sched_barrier(0);

        // s5: S^T = K Q^T + bias + pen
        const __hip_bfloat16* Kb = &Kl[kt & 1][0];
        float s[4][4];
#pragma unroll
        for (int nkb = 0; nkb < 4; ++nkb) {
            f32x4 a = {};
#pragma unroll
            for (int half = 0; half < 2; ++half) {
                bf16x8 kf = *(const bf16x8*)
                    &Kb[(nkb * 16 + lr) * 64 + ((half * 32 + lg * 8) ^ swz)];
                a = __builtin_amdgcn_mfma_f32_16x16x32_bf16(kf, qf[half], a, 0, 0, 0);
            }
            f32x4 pen = *(const f32x4*)&Pen[kt * 64 + nkb * 16 + lg * 4];
#pragma unroll
            for (int j = 0; j < 4; ++j) s[nkb][j] = a[j] + bcur[nkb][j] + pen[j];
        }

        // s6: online softmax (row lane-local; cross-lane over lg groups only)
        float tm = s[0][0];
#pragma unroll
        for (int nkb = 0; nkb < 4; ++nkb)
#pragma unroll
            for (int j = 0; j < 4; ++j) tm = fmaxf(tm, s[nkb][j]);
        tm = fmaxf(tm, __shfl_xor(tm, 16));
        tm = fmaxf(tm, __shfl_xor(tm, 32));
        const float mn = fmaxf(m_, tm);
        const float al = __expf(m_ - mn);
        m_ = mn;
        float ts = 0.f;
#pragma unroll
        for (int nkb = 0; nkb < 4; ++nkb)
#pragma unroll
            for (int j = 0; j < 4; ++j) {
                float p = __expf(s[nkb][j] - mn);
                s[nkb][j] = p;
                ts += p;
            }
        ts += __shfl_xor(ts, 16);
        ts += __shfl_xor(ts, 32);
        l_ = l_ * al + ts;

        // P -> wave-private LDS
#pragma unroll
        for (int nkb = 0; nkb < 4; ++nkb) {
            __hip_bfloat16 pk[4];
#pragma unroll
            for (int j = 0; j < 4; ++j) pk[j] = __float2bfloat16(s[nkb][j]);
            *(short4*)&Pl[w][lr][nkb * 16 + lg * 4] = *(const short4*)pk;
        }

        // rescale acc
        float alr[4];
#pragma unroll
        for (int j = 0; j < 4; ++j) alr[j] = __shfl(al, lg * 4 + j);
#pragma unroll
        for (int db = 0; db < 4; ++db)
#pragma unroll
            for (int j = 0; j < 4; ++j) acc[db][j] *= alr[j];

        // s7: O += P V  (reads Vl[kt&1]; MFMA consumes all ds_reads pre-barrier)
        const __hip_bfloat16* Vb = &Vl[kt & 1][0];
        bf16x8 paf[2];
        paf[0] = *(const bf16x8*)&Pl[w][lr][lg * 8];
        paf[1] = *(const bf16x8*)&Pl[w][lr][32 + lg * 8];
#pragma unroll
        for (int db = 0; db < 4; ++db)
#pragma unroll
            for (int mh = 0; mh < 2; ++mh) {
                bf16x8 vf = *(const bf16x8*)
                    &Vb[(db * 16 + lr) * 64 + ((mh * 32 + lg * 8) ^ swz)];
                acc[db] = __builtin_amdgcn_mfma_f32_16x16x32_bf16(paf[mh], vf,
                                                                  acc[db], 0, 0, 0);
            }

        // s8: rotate bias regs (SSA under full unroll; wait lands at next use)
#pragma unroll
        for (int nkb = 0; nkb < 4; ++nkb) bcur[nkb] = bnxt[nkb];

        // s9: all reads of buf[kt&1] done before any wave's next s1 overwrite
        __builtin_amdgcn_sched_barrier(0);
        __builtin_amdgcn_s_barrier();
        __builtin_amdgcn_sched_barrier(0);
    }

    // keep clamped tail prefetch alive (anti-DCE, keeps vmcnt counts exact)
    float dummy = 0.f;
#pragma unroll
    for (int nkb = 0; nkb < 4; ++nkb) dummy += bcur[nkb][0];
    asm volatile("" :: "v"(dummy));

    // epilogue
    float linv[4];
#pragma unroll
    for (int j = 0; j < 4; ++j) linv[j] = 1.f / __shfl(l_, lg * 4 + j);
#pragma unroll
    for (int db = 0; db < 4; ++db)
#pragma unroll
        for (int j = 0; j < 4; ++j)
            ao[((size_t)b * N_ + orow_base + j) * C_ + h * 64 + db * 16 + lr] =
                __float2bfloat16(acc[db][j] * linv[j]);
}

// ---------------------------------------------------------------- launcher
extern "C" void kernel_launch(void* const* d_in, const int* in_sizes, int n_in,
                              void* d_out, int out_size, void* d_ws, size_t ws_size,
                              hipStream_t stream) {
    const float* x    = (const float*)d_in[0];
    const float* bias = (const float*)d_in[1];
    const int*   mask = (const int*)d_in[2];
    const float* Wq   = (const float*)d_in[3];
    const float* bq   = (const float*)d_in[4];
    const float* Wk   = (const float*)d_in[5];
    const float* bk   = (const float*)d_in[6];
    const float* Wv   = (const float*)d_in[7];
    const float* bv   = (const float*)d_in[8];
    const float* Wo   = (const float*)d_in[9];
    const float* bo   = (const float*)d_in[10];
    float* out = (float*)d_out;

    char* ws = (char*)d_ws;
    const size_t MB = 1u << 20;
    __hip_bfloat16* xb  = (__hip_bfloat16*)(ws + 0 * MB);   // 8 MB
    __hip_bfloat16* wqb = (__hip_bfloat16*)(ws + 8 * MB);   // 2 MB each
    __hip_bfloat16* wkb = (__hip_bfloat16*)(ws + 10 * MB);
    __hip_bfloat16* wvb = (__hip_bfloat16*)(ws + 12 * MB);
    __hip_bfloat16* wob = (__hip_bfloat16*)(ws + 14 * MB);
    __hip_bfloat16* qb  = (__hip_bfloat16*)(ws + 16 * MB);  // 8 MB
    __hip_bfloat16* kb  = (__hip_bfloat16*)(ws + 24 * MB);  // 8 MB
    __hip_bfloat16* vtb = (__hip_bfloat16*)(ws + 32 * MB);  // 8 MB
    __hip_bfloat16* aob = (__hip_bfloat16*)(ws + 40 * MB);  // 8 MB

    f2b_kernel<<<4096, 256, 0, stream>>>(x, xb, B_ * N_ * C_);
    f2b4_kernel<<<dim3(1024, 4), 256, 0, stream>>>(Wq, Wk, Wv, Wo, wqb, wkb, wvb, wob);

    gemm_qkv<<<dim3(24, 32), 256, 0, stream>>>(xb, wqb, wkb, wvb, bq, bk, bv, qb, kb, vtb);

    attn_kernel<<<B_ * H_ * (N_ / 64), 256, 0, stream>>>(qb, kb, vtb, bias, mask, aob);

    gemm_out<<<dim3(8, 32), 256, 0, stream>>>(aob, wob, bo, out);
}